// Round 9
// baseline (153.034 us; speedup 1.0000x reference)
//
#include <hip/hip_runtime.h>

// Radon transform: data (1,1,512,512) f32, angles (256,) f32 -> out (1,1,256,512) f32.
// Block = (angle, 64-col x-chunk), 512 threads. Vertical-pair-packed f16 image
// (word = (img[r][c], img[r+1][c])) so one bilinear sample = one ds_read2_b32 +
// 2 fdot2 + 2 fma. R8/R9: software-pipelined DOUBLE-BUFFERED LDS (AITER pattern):
// prefetch chunk k+1 via global_load_lds while sampling chunk k, with manual
// s_waitcnt vmcnt(12) + raw s_barrier — the DMA stays in flight across the
// barrier instead of the __syncthreads vmcnt(0) drain that capped R4-R7 at ~65us.

#define HH 512
#define WW 512
#define NA 256
#define XC 64
#define YC 64
#define NXC 8
#define NYC 8
#define NW 8                    // waves per block
#define RM 96                   // staged rows (12 per wave, fixed)
#define SM 97                   // word stride: 95 (c>=0) / 97 (c<0); alloc max
#define PAD 112                 // >= 256*sqrt(2)-256+2
#define PW (WW + 2 * PAD)       // 736
#define PH (HH + 2 * PAD)       // 736

typedef __fp16 h2 __attribute__((ext_vector_type(2)));

#if __has_builtin(__builtin_amdgcn_fdot2)
#define FDOT2(a, b, cc) __builtin_amdgcn_fdot2((a), (b), (cc), false)
#else
static __device__ __forceinline__ float FDOT2(h2 a, h2 b, float cc) {
    return fmaf((float)a.x, (float)b.x, fmaf((float)a.y, (float)b.y, cc));
}
#endif

static __device__ __forceinline__ unsigned pack_pair(float v0, float v1) {
    h2 p = __builtin_amdgcn_cvt_pkrtz(v0, v1);
    return __builtin_bit_cast(unsigned, p);
}

// Pv[r][c] = f16x2( P[r][c], P[r+1][c] ), P = zero-padded fp32 image.
__global__ __launch_bounds__(256) void padpack_kernel(
    const float* __restrict__ img, unsigned* __restrict__ Pv)
{
    const int c = blockIdx.x * 256 + threadIdx.x;
    const int r = blockIdx.y;
    if (c >= PW) return;
    const int gr = r - PAD, gc = c - PAD;
    float v0 = 0.0f, v1 = 0.0f;
    if ((unsigned)gc < (unsigned)WW) {
        if ((unsigned)gr       < (unsigned)HH) v0 = img[gr * WW + gc];
        if ((unsigned)(gr + 1) < (unsigned)HH) v1 = img[(gr + 1) * WW + gc];
    }
    Pv[r * PW + c] = pack_pair(v0, v1);
}

// Correctness-only fallback if d_ws is too small (never expected): naive per-column.
__global__ __launch_bounds__(512) void radon_fallback(
    const float* __restrict__ img, const float* __restrict__ angles,
    float* __restrict__ out)
{
    const int x = threadIdx.x, a = blockIdx.x;
    float s, c;
    sincosf(angles[a], &s, &c);
    const float u = (float)x + (0.5f - 256.0f);
    const float cu = fmaf(c, u, 255.5f), cv = fmaf(-s, u, 255.5f);
    float acc = 0.0f;
    for (int y = 0; y < HH; ++y) {
        const float vy = (float)y + (0.5f - 256.0f);
        const float ix = fmaf(s, vy, cu), iy = fmaf(c, vy, cv);
        const float fx = floorf(ix), fy = floorf(iy);
        const int xi = (int)fx, yi = (int)fy;
        const float wx1 = ix - fx, wy1 = iy - fy;
        const float mx0 = ((unsigned)xi       < (unsigned)WW) ? 1.0f - wx1 : 0.0f;
        const float mx1 = ((unsigned)(xi + 1) < (unsigned)WW) ? wx1 : 0.0f;
        const float my0 = ((unsigned)yi       < (unsigned)HH) ? 1.0f - wy1 : 0.0f;
        const float my1 = ((unsigned)(yi + 1) < (unsigned)HH) ? wy1 : 0.0f;
        const int x0 = min(max(xi, 0), WW - 1), x1 = min(max(xi + 1, 0), WW - 1);
        const int y0 = min(max(yi, 0), HH - 1), y1 = min(max(yi + 1, 0), HH - 1);
        acc = fmaf(my0, fmaf(mx1, img[y0 * WW + x1], mx0 * img[y0 * WW + x0]), acc);
        acc = fmaf(my1, fmaf(mx1, img[y1 * WW + x1], mx0 * img[y1 * WW + x0]), acc);
    }
    out[a * WW + x] = acc;
}

template <int S>
__global__ __launch_bounds__(512, 4) void radon_kernel(
    const unsigned* __restrict__ Pv, const float* __restrict__ angles,
    float* __restrict__ out)
{
    __shared__ unsigned tileA[RM * SM];   // 37248 B
    __shared__ unsigned tileB[RM * SM];   // 37248 B
    __shared__ float red[512];            // total 76544 B -> 2 blocks/CU

    const int tid  = threadIdx.x;
    const int lane = tid & 63;
    const int wid  = tid >> 6;

    const int a  = blockIdx.x >> 3;
    const int x0 = (blockIdx.x & 7) * XC;

    float s, c;
    sincosf(angles[a], &s, &c);
    if ((S == 95) != (c >= 0.0f)) return;   // other template instance handles it

    const float u  = (float)(x0 + lane) + (0.5f - 256.0f);
    const float u0 = (float)x0 + (0.5f - 256.0f);
    const float u1 = u0 + 63.0f;

    // block-uniform hoisted bbox pieces (s >= 0 for angles in [0,pi))
    const float cu0 = c * u0, cu1 = c * u1;
    const float cumin = fminf(cu0, cu1), cumax = fmaxf(cu0, cu1);
    const float su0 = -s * u0, su1 = -s * u1;
    const float sumin = fminf(su0, su1), sumax = fmaxf(su0, su1);

    const float bcc = fmaf(c, u, 255.5f);    // global col coord at v-offset 0
    const float brc = fmaf(-s, u, 255.5f);   // global row coord

    const unsigned* __restrict__ Porg = Pv + PAD * PW + PAD;

    // ---- bbox for chunk yc (block-uniform); clamped so staging addresses are
    // always inside the padded buffer (clamp never binds for sampled chunks) ----
    auto bbox = [&](int yc, int& clo, int& rlo, bool& outside) {
        const float v0 = (float)(yc * YC) + (0.5f - 256.0f);
        const float v1 = v0 + 63.0f;
        const float sv0 = s * v0, sv1 = s * v1;            // s>=0: min=sv0,max=sv1
        const float cv0 = c * v0, cv1 = c * v1;
        const float cvmin = fminf(cv0, cv1), cvmax = fmaxf(cv0, cv1);
        const int c_lo = (int)floorf(cumin + sv0 + 255.5f);
        const int c_hi = (int)floorf(cumax + sv1 + 255.5f) + 1;
        const int r_lo = (int)floorf(sumin + cvmin + 255.5f);
        const int r_hi = (int)floorf(sumax + cvmax + 255.5f) + 1;
        outside = (c_lo > WW - 1) | (c_hi < 0) | (r_lo > HH - 1) | (r_hi < 0);
        clo = min(max(c_lo, -PAD), WW + PAD - 96);
        rlo = min(max(r_lo, -PAD), HH + PAD - 96);
    };

    // ---- issue 12 global_load_lds per wave into dst (96 rows x 92 words) ----
    auto stage = [&](unsigned* dst, int clo, int rlo) {
        if (lane < 23) {
            const unsigned* g = Porg + (rlo + wid) * PW + clo + lane * 4;
            int loff = wid * S;
#pragma unroll
            for (int k = 0; k < 12; ++k) {
                __builtin_amdgcn_global_load_lds(
                    (const __attribute__((address_space(1))) void*)g,
                    (__attribute__((address_space(3))) void*)&dst[loff],
                    16, 0, 0);
                g += NW * PW;
                loff += NW * S;
            }
        }
    };

    float acc = 0.0f;

    int clo_cur, rlo_cur; bool out_cur;
    bbox(0, clo_cur, rlo_cur, out_cur);
    stage(tileA, clo_cur, rlo_cur);            // prologue: chunk 0 -> A

    for (int k = 0; k < NYC; ++k) {
        int clo_nxt = 0, rlo_nxt = 0; bool out_nxt = false;
        if (k + 1 < NYC) {
            bbox(k + 1, clo_nxt, rlo_nxt, out_nxt);
            stage((k + 1) & 1 ? tileB : tileA, clo_nxt, rlo_nxt);  // prefetch
            asm volatile("s_waitcnt vmcnt(12)" ::: "memory");  // chunk-k loads done
        } else {
            asm volatile("s_waitcnt vmcnt(0)" ::: "memory");
        }
        __builtin_amdgcn_s_barrier();          // all waves' chunk-k data in LDS

        if (!out_cur) {
            const unsigned* __restrict__ tile = (k & 1) ? tileB : tileA;
            const float bc = bcc - (float)clo_cur;
            const float br = brc - (float)rlo_cur;
            const float vyb = (float)(k * YC) + (0.5f - 256.0f) + (float)(wid * 8);
            const float cx0 = fmaf(s, vyb, bc);
            const float rx0 = fmaf(c, vyb, br);
#pragma unroll
            for (int i = 0; i < 8; ++i) {
                const float cxl = fmaf(s, (float)i, cx0);   // local col >= 0
                const float rxl = fmaf(c, (float)i, rx0);   // local row >= 0
                const int ci = (int)cxl;                    // == floor (>=0)
                const int ri = (int)rxl;
                const float wx1 = __builtin_amdgcn_fractf(cxl);
                const float wy1 = __builtin_amdgcn_fractf(rxl);
                const float wx0 = 1.0f - wx1;
                const float wy0 = 1.0f - wy1;
                const h2 wy = __builtin_amdgcn_cvt_pkrtz(wy0, wy1);

                __builtin_assume(ri >= 0 && ri < RM - 1);
                __builtin_assume(ci >= 0 && ci < 92);
                const int ad = ri * S + ci;

                const unsigned w0 = tile[ad];       // (v00,v10) one ds_read2_b32
                const unsigned w1 = tile[ad + 1];   // (v01,v11)
                const float left  = FDOT2(__builtin_bit_cast(h2, w0), wy, 0.0f);
                const float right = FDOT2(__builtin_bit_cast(h2, w1), wy, 0.0f);
                acc = fmaf(wx0, left, acc);
                acc = fmaf(wx1, right, acc);
            }
        }
        __builtin_amdgcn_s_barrier();          // sampling done before buf reuse

        clo_cur = clo_nxt; rlo_cur = rlo_nxt; out_cur = out_nxt;
    }

    // reduce the 8 y-groups per column and store (each block owns its outputs)
    __syncthreads();
    red[tid] = acc;
    __syncthreads();
    if (tid < 64) {
        float r = red[tid];
#pragma unroll
        for (int k = 1; k < NW; ++k) r += red[k * 64 + tid];
        out[a * WW + x0 + tid] = r;
    }
}

extern "C" void kernel_launch(void* const* d_in, const int* in_sizes, int n_in,
                              void* d_out, int out_size, void* d_ws, size_t ws_size,
                              hipStream_t stream) {
    const float* img    = (const float*)d_in[0];
    const float* angles = (const float*)d_in[1];
    float* out   = (float*)d_out;
    unsigned* Pv = (unsigned*)d_ws;

    if (ws_size >= (size_t)PW * PH * sizeof(unsigned)) {
        padpack_kernel<<<dim3((PW + 255) / 256, PH), 256, 0, stream>>>(img, Pv);
        // both stride variants launched; each block early-exits in the wrong one
        radon_kernel<95><<<dim3(NA * NXC), 512, 0, stream>>>(Pv, angles, out);
        radon_kernel<97><<<dim3(NA * NXC), 512, 0, stream>>>(Pv, angles, out);
    } else {
        radon_fallback<<<dim3(NA), 512, 0, stream>>>(img, angles, out);
    }
}